// Round 8
// baseline (328.683 us; speedup 1.0000x reference)
//
#include <hip/hip_runtime.h>
#include <hip/hip_bf16.h>
#include <math.h>

#define BH_ 32
#define N_ 4096
#define D_ 64
#define SAMP_ 256
#define SCALE_ 0.125f
#define LOG16_ 2.7725887222397811f
#define HPAD 68

typedef __attribute__((ext_vector_type(4))) float f32x4;
typedef __attribute__((ext_vector_type(8))) short bf16x8;
typedef __attribute__((ext_vector_type(4))) short bf16x4;

static __device__ __forceinline__ unsigned pack2(float a, float b) {
    union { __hip_bfloat162 h; unsigned u; } c;
    c.h = __float22bfloat162_rn(make_float2(a, b));
    return c.u;
}

static __device__ __forceinline__ bf16x8 cvt8v(f32x4 a, f32x4 b) {
    union { unsigned u[4]; bf16x8 v; } r;
    r.u[0] = pack2(a[0], a[1]); r.u[1] = pack2(a[2], a[3]);
    r.u[2] = pack2(b[0], b[1]); r.u[3] = pack2(b[2], b[3]);
    return r.v;
}

static __device__ __forceinline__ bf16x8 cvt8(const float* p) {
    return cvt8v(*(const f32x4*)p, *(const f32x4*)(p + 4));
}

// ---------------- 1. LSH hash (unchanged, f64 matches np ref) ---------------
__global__ __launch_bounds__(128) void hash_kernel(
    const float* __restrict__ q, const float* __restrict__ k,
    const float* __restrict__ pd,
    unsigned char* __restrict__ qbuck, unsigned char* __restrict__ kbuck)
{
    extern __shared__ char smraw[];
    float*  Xs  = (float*)smraw;
    double* Pdl = (double*)(smraw + 128 * HPAD * 4);

    int tid = threadIdx.x;
    const float* src = blockIdx.y ? k : q;
    unsigned char* dst = blockIdx.y ? kbuck : qbuck;
    size_t tok0 = (size_t)blockIdx.x * 128;

    {
        int d = tid >> 1, r0 = (tid & 1) * 4;
#pragma unroll
        for (int j = 0; j < 4; ++j)
            Pdl[d * 8 + r0 + j] = (double)pd[d * 8 + r0 + j];
    }
    {
        const float4* src4 = (const float4*)(src + tok0 * D_);
        for (int i = tid; i < 128 * 16; i += 128) {
            int r = i >> 4, c = i & 15;
            *(float4*)&Xs[r * HPAD + c * 4] = src4[i];
        }
    }
    __syncthreads();

    float xr[64];
#pragma unroll
    for (int c = 0; c < 16; ++c)
        *(f32x4*)&xr[c * 4] = *(const f32x4*)&Xs[tid * HPAD + c * 4];

    double acc[8];
#pragma unroll
    for (int r = 0; r < 8; ++r) acc[r] = 0.0;
#pragma unroll
    for (int d = 0; d < 64; ++d) {
        double x = (double)xr[d];
        const double* pr = Pdl + d * 8;
#pragma unroll
        for (int r = 0; r < 8; ++r) acc[r] += x * pr[r];
    }
    int bin = 0;
#pragma unroll
    for (int r = 0; r < 8; ++r)
        if (acc[r] > 0.0) bin |= (1 << r);
    dst[tok0 + tid] = (unsigned char)(bin ^ (bin >> 1));
}

// ---------------- 2. stable counting sort (unchanged) -----------------------
__global__ __launch_bounds__(256) void sort_kernel(
    const unsigned char* __restrict__ qbuck,
    const unsigned char* __restrict__ kbuck,
    int* __restrict__ q_idx, int* __restrict__ k_idx)
{
    __shared__ unsigned short hist[64][256];
    __shared__ unsigned int   binstart[256];
    __shared__ alignas(16) unsigned char bl[N_];

    int bh = blockIdx.x, tensor = blockIdx.y;
    const unsigned char* buck = (tensor ? kbuck : qbuck) + bh * N_;
    int* idx_out = (tensor ? k_idx : q_idx) + bh * N_;
    int t = threadIdx.x;

    ((uint4*)bl)[t] = ((const uint4*)buck)[t];
    {
        uint4* h4 = (uint4*)&hist[0][0];
        for (int i = t; i < 2048; i += 256) h4[i] = make_uint4(0, 0, 0, 0);
    }
    __syncthreads();

    if (t < 64) {
        for (int u = 0; u < 64; ++u) hist[t][bl[t * 64 + u]]++;
    }
    __syncthreads();

    {
        unsigned run = 0;
        for (int tt = 0; tt < 64; ++tt) {
            unsigned c = hist[tt][t];
            hist[tt][t] = (unsigned short)run;
            run += c;
        }
        binstart[t] = run;
    }
    __syncthreads();

    if (t < 64) {
        unsigned b0 = binstart[t*4], b1 = binstart[t*4+1],
                 b2 = binstart[t*4+2], b3 = binstart[t*4+3];
        unsigned s = b0 + b1 + b2 + b3, p = s;
#pragma unroll
        for (int d = 1; d < 64; d <<= 1) {
            unsigned y = __shfl_up(p, d);
            if (t >= d) p += y;
        }
        unsigned e = p - s;
        binstart[t*4]   = e;
        binstart[t*4+1] = e + b0;
        binstart[t*4+2] = e + b0 + b1;
        binstart[t*4+3] = e + b0 + b1 + b2;
    }
    __syncthreads();

    if (t < 64) {
        for (int u = 0; u < 64; ++u) {
            int tok = t * 64 + u;
            int b = bl[tok];
            int pos = (int)(binstart[b] + hist[t][b]);
            hist[t][b]++;
            idx_out[pos] = tok;
        }
    }
}

// ---------------- 3. fused attention: wave-autonomous, no barriers ----------
// 1024 wgs x 512 thr (8 waves). Each wave owns 16 sorted queries and loops
// over 16 chunks of 32 keys (8 block-diag + 8 sampled), fully independently:
// K is gathered global->register directly in MFMA A-fragment shape (row-slice
// per lane); V goes through a 4KB wave-private LDS slice laid out for
// ds_read_b64_tr_b16 (byte = keyquad*512 + dt*128 + kin*32 + d8*16; verified
// mapping from R4-R6). Software pipeline: indices 2 chunks ahead, K/V data
// 1 chunk ahead, all wave-internal. No __syncthreads anywhere in the loop ->
// waves drift, stalls decorrelate, ~10 gathers in flight per wave.
__global__ __launch_bounds__(512, 4) void fused_attn(
    const float* __restrict__ query, const float* __restrict__ key,
    const float* __restrict__ value, const int* __restrict__ q_idx,
    const int* __restrict__ k_idx, const int* __restrict__ sampled,
    float* __restrict__ out)
{
    __shared__ __align__(16) short Vsm[8 * 2048];   // 8 waves x 4KB
    int wg = blockIdx.x, bh = wg >> 5, qb128 = wg & 31;
    int tid = threadIdx.x, w = tid >> 6, l = tid & 63, lg = l >> 4, ll = l & 15;
    size_t base = (size_t)bh * N_;

    const int* kidxA = k_idx + base + (qb128 >> 1) * 256;   // 256 block keys
    const int* kidxB = sampled + bh * SAMP_;                // 256 sampled keys

    short* Vw = &Vsm[w * 2048];
    unsigned vtr = (unsigned)(unsigned long long)(void*)Vw + lg * 512 + ll * 8;

    // V staging decomposition: lane handles tids {l+64*i}, i=0..3 of the
    // 256-slot (32key x 8 d-groups) chunk map.
    int dv8  = ((l >> 3) & 3) * 2 + (l & 1);        // d-group (x8 floats)
    int kbse = (l >> 5) * 4 + ((l >> 1) & 3);       // v-key base (+8i)

    // Q fragment (16 queries per wave)
    const int* qidx = q_idx + base + qb128 * 128 + w * 16;
    int qr = qidx[ll];
    const float* qp = query + (base + (size_t)qr) * D_ + lg * 8;
    bf16x8 qf[2] = { cvt8(qp), cvt8(qp + 32) };

    f32x4 o[4];
#pragma unroll
    for (int dt = 0; dt < 4; ++dt) { f32x4 z = {0.f,0.f,0.f,0.f}; o[dt] = z; }
    float lsum = 0.f;

    // ---- prologue: idx(0) -> data(0); idx(1)
    const int* s0 = kidxA;
    int ki0 = s0[ll], ki1 = s0[16 + ll];
    int va0 = s0[kbse], va1 = s0[kbse + 8], va2 = s0[kbse + 16], va3 = s0[kbse + 24];

    f32x4 vld[8], kld[8];
    {
        const float* vp0 = value + (base + (size_t)va0) * D_ + dv8 * 8;
        const float* vp1 = value + (base + (size_t)va1) * D_ + dv8 * 8;
        const float* vp2 = value + (base + (size_t)va2) * D_ + dv8 * 8;
        const float* vp3 = value + (base + (size_t)va3) * D_ + dv8 * 8;
        vld[0] = *(const f32x4*)vp0; vld[1] = *(const f32x4*)(vp0 + 4);
        vld[2] = *(const f32x4*)vp1; vld[3] = *(const f32x4*)(vp1 + 4);
        vld[4] = *(const f32x4*)vp2; vld[5] = *(const f32x4*)(vp2 + 4);
        vld[6] = *(const f32x4*)vp3; vld[7] = *(const f32x4*)(vp3 + 4);
        const float* kp0 = key + (base + (size_t)ki0) * D_ + lg * 8;
        const float* kp1 = key + (base + (size_t)ki1) * D_ + lg * 8;
        kld[0] = *(const f32x4*)kp0;        kld[1] = *(const f32x4*)(kp0 + 4);
        kld[2] = *(const f32x4*)(kp0 + 32); kld[3] = *(const f32x4*)(kp0 + 36);
        kld[4] = *(const f32x4*)kp1;        kld[5] = *(const f32x4*)(kp1 + 4);
        kld[6] = *(const f32x4*)(kp1 + 32); kld[7] = *(const f32x4*)(kp1 + 36);
    }
    const int* s1 = kidxA + 32;
    int nki0 = s1[ll], nki1 = s1[16 + ll];
    int nva0 = s1[kbse], nva1 = s1[kbse + 8], nva2 = s1[kbse + 16], nva3 = s1[kbse + 24];

    for (int c = 0; c < 16; ++c) {
        // ---- consume chunk c raw data: V -> LDS (tr layout), K -> frags
        bf16x8 kf0a, kf0b, kf1a, kf1b;
        {
            bf16x8 vw0 = cvt8v(vld[0], vld[1]);
            bf16x8 vw1 = cvt8v(vld[2], vld[3]);
            bf16x8 vw2 = cvt8v(vld[4], vld[5]);
            bf16x8 vw3 = cvt8v(vld[6], vld[7]);
            *(bf16x8*)&Vw[(l      ) * 8] = vw0;
            *(bf16x8*)&Vw[(l +  64) * 8] = vw1;
            *(bf16x8*)&Vw[(l + 128) * 8] = vw2;
            *(bf16x8*)&Vw[(l + 192) * 8] = vw3;
            kf0a = cvt8v(kld[0], kld[1]);
            kf0b = cvt8v(kld[2], kld[3]);
            kf1a = cvt8v(kld[4], kld[5]);
            kf1b = cvt8v(kld[6], kld[7]);
        }

        // ---- issue chunk c+1 data loads (idx already in regs)
        if (c < 15) {
            const float* vp0 = value + (base + (size_t)nva0) * D_ + dv8 * 8;
            const float* vp1 = value + (base + (size_t)nva1) * D_ + dv8 * 8;
            const float* vp2 = value + (base + (size_t)nva2) * D_ + dv8 * 8;
            const float* vp3 = value + (base + (size_t)nva3) * D_ + dv8 * 8;
            vld[0] = *(const f32x4*)vp0; vld[1] = *(const f32x4*)(vp0 + 4);
            vld[2] = *(const f32x4*)vp1; vld[3] = *(const f32x4*)(vp1 + 4);
            vld[4] = *(const f32x4*)vp2; vld[5] = *(const f32x4*)(vp2 + 4);
            vld[6] = *(const f32x4*)vp3; vld[7] = *(const f32x4*)(vp3 + 4);
            const float* kp0 = key + (base + (size_t)nki0) * D_ + lg * 8;
            const float* kp1 = key + (base + (size_t)nki1) * D_ + lg * 8;
            kld[0] = *(const f32x4*)kp0;        kld[1] = *(const f32x4*)(kp0 + 4);
            kld[2] = *(const f32x4*)(kp0 + 32); kld[3] = *(const f32x4*)(kp0 + 36);
            kld[4] = *(const f32x4*)kp1;        kld[5] = *(const f32x4*)(kp1 + 4);
            kld[6] = *(const f32x4*)(kp1 + 32); kld[7] = *(const f32x4*)(kp1 + 36);
        }
        // ---- issue chunk c+2 idx loads
        if (c < 14) {
            int cn = c + 2;
            const int* sn = (cn < 8) ? (kidxA + cn * 32) : (kidxB + (cn - 8) * 32);
            nki0 = sn[ll]; nki1 = sn[16 + ll];
            nva0 = sn[kbse]; nva1 = sn[kbse + 8];
            nva2 = sn[kbse + 16]; nva3 = sn[kbse + 24];
        }

        // ---- QK^T (swapped): S^T rows key = t*16 + lg*4 + r, col q = ll
        float bias = (c < 8) ? 0.f : LOG16_;
        f32x4 sA = {0.f,0.f,0.f,0.f}, sB = {0.f,0.f,0.f,0.f};
        sA = __builtin_amdgcn_mfma_f32_16x16x32_bf16(kf0a, qf[0], sA, 0, 0, 0);
        sA = __builtin_amdgcn_mfma_f32_16x16x32_bf16(kf0b, qf[1], sA, 0, 0, 0);
        sB = __builtin_amdgcn_mfma_f32_16x16x32_bf16(kf1a, qf[0], sB, 0, 0, 0);
        sB = __builtin_amdgcn_mfma_f32_16x16x32_bf16(kf1b, qf[1], sB, 0, 0, 0);

        f32x4 eA, eB;
#pragma unroll
        for (int r = 0; r < 4; ++r) {
            eA[r] = __expf(fmaf(sA[r], SCALE_, bias));
            eB[r] = __expf(fmaf(sB[r], SCALE_, bias));
        }
        lsum += (eA[0] + eA[1]) + (eA[2] + eA[3]) +
                (eB[0] + eB[1]) + (eB[2] + eB[3]);
        bf16x8 pb;
        { union { unsigned u[4]; bf16x8 v; } pc;
          pc.u[0] = pack2(eA[0], eA[1]); pc.u[1] = pack2(eA[2], eA[3]);
          pc.u[2] = pack2(eB[0], eB[1]); pc.u[3] = pack2(eB[2], eB[3]);
          pb = pc.v; }

        // ---- ensure V writes visible, then tr-read + PV per dt
        __builtin_amdgcn_sched_barrier(0);
        asm volatile("s_waitcnt lgkmcnt(0)" ::: "memory");
#pragma unroll
        for (int dt = 0; dt < 4; ++dt) {
            bf16x4 t0, t1;
            asm volatile("ds_read_b64_tr_b16 %0, %1 offset:%2"
                         : "=v"(t0) : "v"(vtr), "i"(dt * 128));
            asm volatile("ds_read_b64_tr_b16 %0, %1 offset:%2"
                         : "=v"(t1) : "v"(vtr), "i"(dt * 128 + 2048));
            asm volatile("s_waitcnt lgkmcnt(0)" ::: "memory");
            __builtin_amdgcn_sched_barrier(0);
            union { bf16x4 h[2]; bf16x8 v; } va;
            va.h[0] = t0; va.h[1] = t1;
            o[dt] = __builtin_amdgcn_mfma_f32_16x16x32_bf16(va.v, pb, o[dt], 0, 0, 0);
        }
    }

    // ---- row-sum over lg groups; epilogue out = o / l
    lsum += __shfl_xor(lsum, 16);
    lsum += __shfl_xor(lsum, 32);

    float dn = 1.f / lsum;
    float* orow = out + (base + (size_t)qr) * D_ + lg * 4;
#pragma unroll
    for (int dt = 0; dt < 4; ++dt) {
        f32x4 v = o[dt] * dn;
        *(f32x4*)&orow[dt * 16] = v;
    }
}

// ---------------------------------------------------------------------------
extern "C" void kernel_launch(void* const* d_in, const int* in_sizes, int n_in,
                              void* d_out, int out_size, void* d_ws, size_t ws_size,
                              hipStream_t stream)
{
    const float* query = (const float*)d_in[0];
    const float* key   = (const float*)d_in[1];
    const float* value = (const float*)d_in[2];
    const float* pd    = (const float*)d_in[3];
    const int*   samp  = (const int*)d_in[4];
    float* out = (float*)d_out;

    char* ws = (char*)d_ws;
    unsigned char* qbuck = (unsigned char*)ws;                 // 128 KB
    unsigned char* kbuck = qbuck + (size_t)BH_ * N_;           // 128 KB
    int* q_idx = (int*)(ws + 262144);                          // 512 KB
    int* k_idx = (int*)(ws + 262144 + 524288);                 // 512 KB

    size_t hash_lds = 128 * HPAD * 4 + 512 * 8;
    hipLaunchKernelGGL(hash_kernel, dim3(BH_ * N_ / 128, 2), dim3(128),
                       hash_lds, stream, query, key, pd, qbuck, kbuck);
    hipLaunchKernelGGL(sort_kernel, dim3(BH_, 2), dim3(256), 0, stream,
                       qbuck, kbuck, q_idx, k_idx);
    hipLaunchKernelGGL(fused_attn, dim3(1024), dim3(512), 0, stream,
                       query, key, value, q_idx, k_idx, samp, out);
}

// Round 9
// 82.934 us; speedup vs baseline: 3.9632x; 3.9632x over previous
//
#include <hip/hip_runtime.h>
#include <hip/hip_bf16.h>
#include <math.h>

#define BH_ 32
#define N_ 4096
#define D_ 64
#define SAMP_ 256
#define SCALE_ 0.125f
#define LOG16_ 2.7725887222397811f
#define HPAD 68

typedef __attribute__((ext_vector_type(4))) float f32x4;
typedef __attribute__((ext_vector_type(8))) short bf16x8;
typedef __attribute__((ext_vector_type(4))) short bf16x4;

static __device__ __forceinline__ unsigned pack2(float a, float b) {
    union { __hip_bfloat162 h; unsigned u; } c;
    c.h = __float22bfloat162_rn(make_float2(a, b));
    return c.u;
}

static __device__ __forceinline__ bf16x8 cvt8v(f32x4 a, f32x4 b) {
    union { unsigned u[4]; bf16x8 v; } r;
    r.u[0] = pack2(a[0], a[1]); r.u[1] = pack2(a[2], a[3]);
    r.u[2] = pack2(b[0], b[1]); r.u[3] = pack2(b[2], b[3]);
    return r.v;
}

static __device__ __forceinline__ bf16x8 cvt8(const float* p) {
    return cvt8v(*(const f32x4*)p, *(const f32x4*)(p + 4));
}

// ---------------- 1. LSH hash (working; ~10us) ------------------------------
__global__ __launch_bounds__(128) void hash_kernel(
    const float* __restrict__ q, const float* __restrict__ k,
    const float* __restrict__ pd,
    unsigned char* __restrict__ qbuck, unsigned char* __restrict__ kbuck)
{
    extern __shared__ char smraw[];
    float*  Xs  = (float*)smraw;
    double* Pdl = (double*)(smraw + 128 * HPAD * 4);

    int tid = threadIdx.x;
    const float* src = blockIdx.y ? k : q;
    unsigned char* dst = blockIdx.y ? kbuck : qbuck;
    size_t tok0 = (size_t)blockIdx.x * 128;

    {
        int d = tid >> 1, r0 = (tid & 1) * 4;
#pragma unroll
        for (int j = 0; j < 4; ++j)
            Pdl[d * 8 + r0 + j] = (double)pd[d * 8 + r0 + j];
    }
    {
        const float4* src4 = (const float4*)(src + tok0 * D_);
        for (int i = tid; i < 128 * 16; i += 128) {
            int r = i >> 4, c = i & 15;
            *(float4*)&Xs[r * HPAD + c * 4] = src4[i];
        }
    }
    __syncthreads();

    float xr[64];
#pragma unroll
    for (int c = 0; c < 16; ++c)
        *(f32x4*)&xr[c * 4] = *(const f32x4*)&Xs[tid * HPAD + c * 4];

    double acc[8];
#pragma unroll
    for (int r = 0; r < 8; ++r) acc[r] = 0.0;
#pragma unroll
    for (int d = 0; d < 64; ++d) {
        double x = (double)xr[d];
        const double* pr = Pdl + d * 8;
#pragma unroll
        for (int r = 0; r < 8; ++r) acc[r] += x * pr[r];
    }
    int bin = 0;
#pragma unroll
    for (int r = 0; r < 8; ++r)
        if (acc[r] > 0.0) bin |= (1 << r);
    dst[tok0 + tid] = (unsigned char)(bin ^ (bin >> 1));
}

// ---------------- 2. stable counting sort (working) -------------------------
__global__ __launch_bounds__(256) void sort_kernel(
    const unsigned char* __restrict__ qbuck,
    const unsigned char* __restrict__ kbuck,
    int* __restrict__ q_idx, int* __restrict__ k_idx)
{
    __shared__ unsigned short hist[64][256];
    __shared__ unsigned int   binstart[256];
    __shared__ alignas(16) unsigned char bl[N_];

    int bh = blockIdx.x, tensor = blockIdx.y;
    const unsigned char* buck = (tensor ? kbuck : qbuck) + bh * N_;
    int* idx_out = (tensor ? k_idx : q_idx) + bh * N_;
    int t = threadIdx.x;

    ((uint4*)bl)[t] = ((const uint4*)buck)[t];
    {
        uint4* h4 = (uint4*)&hist[0][0];
        for (int i = t; i < 2048; i += 256) h4[i] = make_uint4(0, 0, 0, 0);
    }
    __syncthreads();

    if (t < 64) {
        for (int u = 0; u < 64; ++u) hist[t][bl[t * 64 + u]]++;
    }
    __syncthreads();

    {
        unsigned run = 0;
        for (int tt = 0; tt < 64; ++tt) {
            unsigned c = hist[tt][t];
            hist[tt][t] = (unsigned short)run;
            run += c;
        }
        binstart[t] = run;
    }
    __syncthreads();

    if (t < 64) {
        unsigned b0 = binstart[t*4], b1 = binstart[t*4+1],
                 b2 = binstart[t*4+2], b3 = binstart[t*4+3];
        unsigned s = b0 + b1 + b2 + b3, p = s;
#pragma unroll
        for (int d = 1; d < 64; d <<= 1) {
            unsigned y = __shfl_up(p, d);
            if (t >= d) p += y;
        }
        unsigned e = p - s;
        binstart[t*4]   = e;
        binstart[t*4+1] = e + b0;
        binstart[t*4+2] = e + b0 + b1;
        binstart[t*4+3] = e + b0 + b1 + b2;
    }
    __syncthreads();

    if (t < 64) {
        for (int u = 0; u < 64; ++u) {
            int tok = t * 64 + u;
            int b = bl[tok];
            int pos = (int)(binstart[b] + hist[t][b]);
            hist[t][b]++;
            idx_out[pos] = tok;
        }
    }
}

// ---------------- 3. fused attention: 8 phases x 64 keys --------------------
// 512 wgs x 512 thr (8 waves x 32 q). Phases: 4 block-key + 4 sampled-key
// chunks of 64 keys, single-buffered 16KB LDS. One-phase-ahead REGISTER
// prefetch (16 VGPR held). Barrier asymmetry: __syncthreads for stage->compute
// (nothing in flight); raw s_barrier for compute->stage so prefetch global
// loads stay in flight across it (compiler inserts counted vmcnt at the cvt).
// K LDS: [kt(4)][ks(2)][lg(4)][ll(16)][8] shorts -> conflict-free b128 reads.
// V LDS: tr-subtile layout (verified R6/R8), ds_read_b64_tr_b16 consumed.
__global__ __launch_bounds__(512, 4) void fused_attn(
    const float* __restrict__ query, const float* __restrict__ key,
    const float* __restrict__ value, const int* __restrict__ q_idx,
    const int* __restrict__ k_idx, const int* __restrict__ sampled,
    float* __restrict__ out)
{
    __shared__ __align__(16) short Ksm[4096];   // 8 KB (64 keys x 64 d bf16)
    __shared__ __align__(16) short Vsm[4096];   // 8 KB
    int wg = blockIdx.x, bh = wg >> 4, blk = wg & 15;
    int tid = threadIdx.x, w = tid >> 6, l = tid & 63, lg = l >> 4, ll = l & 15;
    size_t base = (size_t)bh * N_;

    // staging decomposition (512 threads <-> 64 keys x 64 d, K and V)
    int krow = tid >> 3, kd8 = tid & 7;
    int kofs = (krow >> 4) * 1024 + (kd8 >> 2) * 512 + (kd8 & 3) * 128 + (krow & 15) * 8;
    int i6 = tid >> 6, l6 = tid & 63;
    int vrow = (i6 >> 2) * 32 + ((l6 >> 5) * 4 + ((l6 >> 1) & 3)) + (i6 & 3) * 8;
    int vd   = (((l6 >> 3) & 3) * 2 + (l6 & 1)) * 8;

    const int* kidxA = k_idx + base + blk * 256;
    const int* kidxB = sampled + bh * SAMP_;

    // Q fragments: wave owns 32 queries (2 mt x 16)
    const int* qidx = q_idx + base + blk * 256 + w * 32;
    int qr[2]; bf16x8 qf[2][2];
#pragma unroll
    for (int mt = 0; mt < 2; ++mt) {
        qr[mt] = qidx[mt * 16 + ll];
        const float* qp = query + (base + (size_t)qr[mt]) * D_;
#pragma unroll
        for (int ks = 0; ks < 2; ++ks)
            qf[mt][ks] = cvt8(qp + ks * 32 + lg * 8);
    }

    f32x4 o[4][2]; float lsum[2];
#pragma unroll
    for (int mt = 0; mt < 2; ++mt) {
        lsum[mt] = 0.f;
#pragma unroll
        for (int dt = 0; dt < 4; ++dt) { f32x4 z = {0.f,0.f,0.f,0.f}; o[dt][mt] = z; }
    }
    unsigned vtr = (unsigned)(unsigned long long)(void*)&Vsm[0] + lg * 512 + ll * 8;

    // prologue: idx(0) -> data(0); idx(1)
    int kI = kidxA[krow], vI = kidxA[vrow];
    f32x4 pk0, pk1, pv0, pv1;
    {
        const float* kp_ = key + (base + (size_t)kI) * D_ + kd8 * 8;
        pk0 = *(const f32x4*)kp_; pk1 = *(const f32x4*)(kp_ + 4);
        const float* vp_ = value + (base + (size_t)vI) * D_ + vd;
        pv0 = *(const f32x4*)vp_; pv1 = *(const f32x4*)(vp_ + 4);
    }
    int kIn = kidxA[64 + krow], vIn = kidxA[64 + vrow];

    for (int c = 0; c < 8; ++c) {
        // ---- stage phase c from prefetch regs (vmcnt waits inserted here)
        *(bf16x8*)&Ksm[kofs]    = cvt8v(pk0, pk1);
        *(bf16x8*)&Vsm[tid * 8] = cvt8v(pv0, pv1);
        __syncthreads();                       // LDS(c) ready (nothing else in flight)

        // ---- issue phase c+1 data + phase c+2 idx (stay in flight across
        //      compute and the raw end barrier)
        if (c < 7) {
            const float* kp_ = key + (base + (size_t)kIn) * D_ + kd8 * 8;
            pk0 = *(const f32x4*)kp_; pk1 = *(const f32x4*)(kp_ + 4);
            const float* vp_ = value + (base + (size_t)vIn) * D_ + vd;
            pv0 = *(const f32x4*)vp_; pv1 = *(const f32x4*)(vp_ + 4);
            if (c < 6) {
                const int* nx = (c + 2 < 4) ? (kidxA + (c + 2) * 64)
                                            : (kidxB + (c - 2) * 64);
                kIn = nx[krow]; vIn = nx[vrow];
            }
        }

        // ---- compute phase c
        float bias = (c < 4) ? 0.f : LOG16_;
#pragma unroll
        for (int ks2 = 0; ks2 < 2; ++ks2) {
            unsigned pbu[2][4];
            __builtin_amdgcn_s_setprio(1);
#pragma unroll
            for (int t = 0; t < 2; ++t) {
                int kt = ks2 * 2 + t;
                f32x4 s0 = {0.f,0.f,0.f,0.f}, s1 = {0.f,0.f,0.f,0.f};
#pragma unroll
                for (int ks = 0; ks < 2; ++ks) {
                    bf16x8 a = *(const bf16x8*)&Ksm[kt * 1024 + ks * 512 + lg * 128 + ll * 8];
                    s0 = __builtin_amdgcn_mfma_f32_16x16x32_bf16(a, qf[0][ks], s0, 0, 0, 0);
                    s1 = __builtin_amdgcn_mfma_f32_16x16x32_bf16(a, qf[1][ks], s1, 0, 0, 0);
                }
                __builtin_amdgcn_s_setprio(0);
                f32x4 e0, e1;
#pragma unroll
                for (int r = 0; r < 4; ++r) {
                    e0[r] = __expf(fmaf(s0[r], SCALE_, bias));
                    e1[r] = __expf(fmaf(s1[r], SCALE_, bias));
                }
                lsum[0] += (e0[0] + e0[1]) + (e0[2] + e0[3]);
                lsum[1] += (e1[0] + e1[1]) + (e1[2] + e1[3]);
                pbu[0][t*2]   = pack2(e0[0], e0[1]);
                pbu[0][t*2+1] = pack2(e0[2], e0[3]);
                pbu[1][t*2]   = pack2(e1[0], e1[1]);
                pbu[1][t*2+1] = pack2(e1[2], e1[3]);
                __builtin_amdgcn_s_setprio(1);
            }
            bf16x8 pb0, pb1;
            { union { unsigned u[4]; bf16x8 v; } cc;
              cc.u[0]=pbu[0][0]; cc.u[1]=pbu[0][1]; cc.u[2]=pbu[0][2]; cc.u[3]=pbu[0][3]; pb0=cc.v; }
            { union { unsigned u[4]; bf16x8 v; } cc;
              cc.u[0]=pbu[1][0]; cc.u[1]=pbu[1][1]; cc.u[2]=pbu[1][2]; cc.u[3]=pbu[1][3]; pb1=cc.v; }

            bf16x4 tr[4][2];
#pragma unroll
            for (int dt = 0; dt < 4; ++dt) {
                asm volatile("ds_read_b64_tr_b16 %0, %1 offset:%2"
                             : "=v"(tr[dt][0]) : "v"(vtr), "i"(ks2 * 4096 + dt * 128));
                asm volatile("ds_read_b64_tr_b16 %0, %1 offset:%2"
                             : "=v"(tr[dt][1]) : "v"(vtr), "i"(ks2 * 4096 + dt * 128 + 2048));
            }
            asm volatile("s_waitcnt lgkmcnt(0)" ::: "memory");
            __builtin_amdgcn_sched_barrier(0);
#pragma unroll
            for (int dt = 0; dt < 4; ++dt) {
                union { bf16x4 h[2]; bf16x8 v; } va;
                va.h[0] = tr[dt][0]; va.h[1] = tr[dt][1];
                o[dt][0] = __builtin_amdgcn_mfma_f32_16x16x32_bf16(va.v, pb0, o[dt][0], 0, 0, 0);
                o[dt][1] = __builtin_amdgcn_mfma_f32_16x16x32_bf16(va.v, pb1, o[dt][1], 0, 0, 0);
            }
            __builtin_amdgcn_s_setprio(0);
        }

        // ---- end barrier: raw s_barrier (does NOT drain vmcnt -> prefetch
        //      loads for c+1 stay in flight). LDS(c) reads are complete
        //      (consumed by MFMAs above); writes for c+1 happen after the
        //      next-iteration stage, pinned by sched_barrier.
        __builtin_amdgcn_sched_barrier(0);
        __builtin_amdgcn_s_barrier();
        __builtin_amdgcn_sched_barrier(0);
    }

    // ---- row-sum over lg groups; epilogue out = o / l
#pragma unroll
    for (int mt = 0; mt < 2; ++mt) {
        float v = lsum[mt];
        v += __shfl_xor(v, 16);
        v += __shfl_xor(v, 32);
        lsum[mt] = v;
    }
#pragma unroll
    for (int mt = 0; mt < 2; ++mt) {
        float dn = 1.f / lsum[mt];
        float* orow = out + (base + (size_t)qr[mt]) * D_ + lg * 4;
#pragma unroll
        for (int dt = 0; dt < 4; ++dt) {
            f32x4 v = o[dt][mt] * dn;
            *(f32x4*)&orow[dt * 16] = v;
        }
    }
}

// ---------------------------------------------------------------------------
extern "C" void kernel_launch(void* const* d_in, const int* in_sizes, int n_in,
                              void* d_out, int out_size, void* d_ws, size_t ws_size,
                              hipStream_t stream)
{
    const float* query = (const float*)d_in[0];
    const float* key   = (const float*)d_in[1];
    const float* value = (const float*)d_in[2];
    const float* pd    = (const float*)d_in[3];
    const int*   samp  = (const int*)d_in[4];
    float* out = (float*)d_out;

    char* ws = (char*)d_ws;
    unsigned char* qbuck = (unsigned char*)ws;                 // 128 KB
    unsigned char* kbuck = qbuck + (size_t)BH_ * N_;           // 128 KB
    int* q_idx = (int*)(ws + 262144);                          // 512 KB
    int* k_idx = (int*)(ws + 262144 + 524288);                 // 512 KB

    size_t hash_lds = 128 * HPAD * 4 + 512 * 8;
    hipLaunchKernelGGL(hash_kernel, dim3(BH_ * N_ / 128, 2), dim3(128),
                       hash_lds, stream, query, key, pd, qbuck, kbuck);
    hipLaunchKernelGGL(sort_kernel, dim3(BH_, 2), dim3(256), 0, stream,
                       qbuck, kbuck, q_idx, k_idx);
    hipLaunchKernelGGL(fused_attn, dim3(512), dim3(512), 0, stream,
                       query, key, value, q_idx, k_idx, samp, out);
}

// Round 10
// 79.096 us; speedup vs baseline: 4.1555x; 1.0485x over previous
//
#include <hip/hip_runtime.h>
#include <hip/hip_bf16.h>
#include <math.h>

#define BH_ 32
#define N_ 4096
#define D_ 64
#define SAMP_ 256
#define SCALE_ 0.125f
#define LOG16_ 2.7725887222397811f
#define HPAD 68

typedef __attribute__((ext_vector_type(4))) float f32x4;
typedef __attribute__((ext_vector_type(8))) short bf16x8;
typedef __attribute__((ext_vector_type(4))) short bf16x4;

static __device__ __forceinline__ unsigned pack2(float a, float b) {
    union { __hip_bfloat162 h; unsigned u; } c;
    c.h = __float22bfloat162_rn(make_float2(a, b));
    return c.u;
}

static __device__ __forceinline__ bf16x8 cvt8v(f32x4 a, f32x4 b) {
    union { unsigned u[4]; bf16x8 v; } r;
    r.u[0] = pack2(a[0], a[1]); r.u[1] = pack2(a[2], a[3]);
    r.u[2] = pack2(b[0], b[1]); r.u[3] = pack2(b[2], b[3]);
    return r.v;
}

static __device__ __forceinline__ bf16x8 cvt8(const float* p) {
    return cvt8v(*(const f32x4*)p, *(const f32x4*)(p + 4));
}

// ---------------- 1. LSH hash (working) -------------------------------------
__global__ __launch_bounds__(128) void hash_kernel(
    const float* __restrict__ q, const float* __restrict__ k,
    const float* __restrict__ pd,
    unsigned char* __restrict__ qbuck, unsigned char* __restrict__ kbuck)
{
    extern __shared__ char smraw[];
    float*  Xs  = (float*)smraw;
    double* Pdl = (double*)(smraw + 128 * HPAD * 4);

    int tid = threadIdx.x;
    const float* src = blockIdx.y ? k : q;
    unsigned char* dst = blockIdx.y ? kbuck : qbuck;
    size_t tok0 = (size_t)blockIdx.x * 128;

    {
        int d = tid >> 1, r0 = (tid & 1) * 4;
#pragma unroll
        for (int j = 0; j < 4; ++j)
            Pdl[d * 8 + r0 + j] = (double)pd[d * 8 + r0 + j];
    }
    {
        const float4* src4 = (const float4*)(src + tok0 * D_);
        for (int i = tid; i < 128 * 16; i += 128) {
            int r = i >> 4, c = i & 15;
            *(float4*)&Xs[r * HPAD + c * 4] = src4[i];
        }
    }
    __syncthreads();

    float xr[64];
#pragma unroll
    for (int c = 0; c < 16; ++c)
        *(f32x4*)&xr[c * 4] = *(const f32x4*)&Xs[tid * HPAD + c * 4];

    double acc[8];
#pragma unroll
    for (int r = 0; r < 8; ++r) acc[r] = 0.0;
#pragma unroll
    for (int d = 0; d < 64; ++d) {
        double x = (double)xr[d];
        const double* pr = Pdl + d * 8;
#pragma unroll
        for (int r = 0; r < 8; ++r) acc[r] += x * pr[r];
    }
    int bin = 0;
#pragma unroll
    for (int r = 0; r < 8; ++r)
        if (acc[r] > 0.0) bin |= (1 << r);
    dst[tok0 + tid] = (unsigned char)(bin ^ (bin >> 1));
}

// ---------------- 2. stable counting sort (working) -------------------------
__global__ __launch_bounds__(256) void sort_kernel(
    const unsigned char* __restrict__ qbuck,
    const unsigned char* __restrict__ kbuck,
    int* __restrict__ q_idx, int* __restrict__ k_idx)
{
    __shared__ unsigned short hist[64][256];
    __shared__ unsigned int   binstart[256];
    __shared__ alignas(16) unsigned char bl[N_];

    int bh = blockIdx.x, tensor = blockIdx.y;
    const unsigned char* buck = (tensor ? kbuck : qbuck) + bh * N_;
    int* idx_out = (tensor ? k_idx : q_idx) + bh * N_;
    int t = threadIdx.x;

    ((uint4*)bl)[t] = ((const uint4*)buck)[t];
    {
        uint4* h4 = (uint4*)&hist[0][0];
        for (int i = t; i < 2048; i += 256) h4[i] = make_uint4(0, 0, 0, 0);
    }
    __syncthreads();

    if (t < 64) {
        for (int u = 0; u < 64; ++u) hist[t][bl[t * 64 + u]]++;
    }
    __syncthreads();

    {
        unsigned run = 0;
        for (int tt = 0; tt < 64; ++tt) {
            unsigned c = hist[tt][t];
            hist[tt][t] = (unsigned short)run;
            run += c;
        }
        binstart[t] = run;
    }
    __syncthreads();

    if (t < 64) {
        unsigned b0 = binstart[t*4], b1 = binstart[t*4+1],
                 b2 = binstart[t*4+2], b3 = binstart[t*4+3];
        unsigned s = b0 + b1 + b2 + b3, p = s;
#pragma unroll
        for (int d = 1; d < 64; d <<= 1) {
            unsigned y = __shfl_up(p, d);
            if (t >= d) p += y;
        }
        unsigned e = p - s;
        binstart[t*4]   = e;
        binstart[t*4+1] = e + b0;
        binstart[t*4+2] = e + b0 + b1;
        binstart[t*4+3] = e + b0 + b1 + b2;
    }
    __syncthreads();

    if (t < 64) {
        for (int u = 0; u < 64; ++u) {
            int tok = t * 64 + u;
            int b = bl[tok];
            int pos = (int)(binstart[b] + hist[t][b]);
            hist[t][b]++;
            idx_out[pos] = tok;
        }
    }
}

// ---------------- 3. fused attention: 2 mega-phases -------------------------
// 512 wgs x 512 thr (8 waves x 32 q). Per phase: ALL 256 keys+values staged
// into 64KB LDS once (3 barriers total in the kernel), then each wave chews
// through 8 chunks of 32 keys with zero barriers and full cross-chunk ILP.
// Phase A = block keys (bias 0), phase B = sampled keys (bias log16, exact
// combine out = o/l). 2 wgs/CU (128KB LDS). B-phase indices prefetched
// during A-compute. XCD-bijective blockIdx swizzle for sampled-key L2 reuse.
// K LDS: [kt(16)][ks(2)][lg(4)][ll(16)][8] shorts; staged by r=tid&255 so
// write conflicts are 4-way (free-ish), reads conflict-free b128.
// V LDS: 4 groups x tr-subtile layout (verified R4-R9), ds_read_b64_tr_b16.
static __device__ __forceinline__ void stage_kv(
    const float* __restrict__ key, const float* __restrict__ value,
    size_t base, int krI, int v0, int v1, int v2, int v3,
    int hK, int kwofs, int vd, int tid, short* Ksm, short* Vsm)
{
    {   // K: one key row half (128B f32) -> 4 bf16x8 chunks
        const float* kp = key + (base + (size_t)krI) * D_ + hK * 32;
        f32x4 k0 = *(const f32x4*)kp,        k1 = *(const f32x4*)(kp + 4);
        f32x4 k2 = *(const f32x4*)(kp + 8),  k3 = *(const f32x4*)(kp + 12);
        f32x4 k4 = *(const f32x4*)(kp + 16), k5 = *(const f32x4*)(kp + 20);
        f32x4 k6 = *(const f32x4*)(kp + 24), k7 = *(const f32x4*)(kp + 28);
        *(bf16x8*)&Ksm[kwofs]       = cvt8v(k0, k1);
        *(bf16x8*)&Ksm[kwofs + 128] = cvt8v(k2, k3);
        *(bf16x8*)&Ksm[kwofs + 256] = cvt8v(k4, k5);
        *(bf16x8*)&Ksm[kwofs + 384] = cvt8v(k6, k7);
    }
    {   // V: 4 groups of 64 keys, one 8-float chunk each, linear LDS writes
        const float* vp0 = value + (base + (size_t)v0) * D_ + vd;
        const float* vp1 = value + (base + (size_t)v1) * D_ + vd;
        const float* vp2 = value + (base + (size_t)v2) * D_ + vd;
        const float* vp3 = value + (base + (size_t)v3) * D_ + vd;
        f32x4 a0 = *(const f32x4*)vp0, b0 = *(const f32x4*)(vp0 + 4);
        f32x4 a1 = *(const f32x4*)vp1, b1 = *(const f32x4*)(vp1 + 4);
        f32x4 a2 = *(const f32x4*)vp2, b2 = *(const f32x4*)(vp2 + 4);
        f32x4 a3 = *(const f32x4*)vp3, b3 = *(const f32x4*)(vp3 + 4);
        *(bf16x8*)&Vsm[tid * 8]         = cvt8v(a0, b0);
        *(bf16x8*)&Vsm[4096 + tid * 8]  = cvt8v(a1, b1);
        *(bf16x8*)&Vsm[8192 + tid * 8]  = cvt8v(a2, b2);
        *(bf16x8*)&Vsm[12288 + tid * 8] = cvt8v(a3, b3);
    }
}

static __device__ __forceinline__ void compute_256(
    const short* __restrict__ Ksm, unsigned vtr, float bias,
    const bf16x8 (&qf)[2][2], int lg, int ll,
    f32x4 (&o)[4][2], float (&lsum)[2])
{
#pragma unroll
    for (int hgi = 0; hgi < 8; ++hgi) {
        unsigned pbu[2][4];
        __builtin_amdgcn_s_setprio(1);
#pragma unroll
        for (int t = 0; t < 2; ++t) {
            int kt = hgi * 2 + t;
            f32x4 s0 = {0.f,0.f,0.f,0.f}, s1 = {0.f,0.f,0.f,0.f};
#pragma unroll
            for (int ks = 0; ks < 2; ++ks) {
                bf16x8 a = *(const bf16x8*)&Ksm[kt * 1024 + ks * 512 + lg * 128 + ll * 8];
                s0 = __builtin_amdgcn_mfma_f32_16x16x32_bf16(a, qf[0][ks], s0, 0, 0, 0);
                s1 = __builtin_amdgcn_mfma_f32_16x16x32_bf16(a, qf[1][ks], s1, 0, 0, 0);
            }
            __builtin_amdgcn_s_setprio(0);
            f32x4 e0, e1;
#pragma unroll
            for (int r = 0; r < 4; ++r) {
                e0[r] = __expf(fmaf(s0[r], SCALE_, bias));
                e1[r] = __expf(fmaf(s1[r], SCALE_, bias));
            }
            lsum[0] += (e0[0] + e0[1]) + (e0[2] + e0[3]);
            lsum[1] += (e1[0] + e1[1]) + (e1[2] + e1[3]);
            pbu[0][t*2]   = pack2(e0[0], e0[1]);
            pbu[0][t*2+1] = pack2(e0[2], e0[3]);
            pbu[1][t*2]   = pack2(e1[0], e1[1]);
            pbu[1][t*2+1] = pack2(e1[2], e1[3]);
            __builtin_amdgcn_s_setprio(1);
        }
        bf16x8 pb0, pb1;
        { union { unsigned u[4]; bf16x8 v; } cc;
          cc.u[0]=pbu[0][0]; cc.u[1]=pbu[0][1]; cc.u[2]=pbu[0][2]; cc.u[3]=pbu[0][3]; pb0=cc.v; }
        { union { unsigned u[4]; bf16x8 v; } cc;
          cc.u[0]=pbu[1][0]; cc.u[1]=pbu[1][1]; cc.u[2]=pbu[1][2]; cc.u[3]=pbu[1][3]; pb1=cc.v; }

        bf16x4 tr[4][2];
#pragma unroll
        for (int dt = 0; dt < 4; ++dt) {
            asm volatile("ds_read_b64_tr_b16 %0, %1 offset:%2"
                         : "=v"(tr[dt][0]) : "v"(vtr), "i"(hgi * 4096 + dt * 128));
            asm volatile("ds_read_b64_tr_b16 %0, %1 offset:%2"
                         : "=v"(tr[dt][1]) : "v"(vtr), "i"(hgi * 4096 + dt * 128 + 2048));
        }
        asm volatile("s_waitcnt lgkmcnt(0)" ::: "memory");
        __builtin_amdgcn_sched_barrier(0);
#pragma unroll
        for (int dt = 0; dt < 4; ++dt) {
            union { bf16x4 h[2]; bf16x8 v; } va;
            va.h[0] = tr[dt][0]; va.h[1] = tr[dt][1];
            o[dt][0] = __builtin_amdgcn_mfma_f32_16x16x32_bf16(va.v, pb0, o[dt][0], 0, 0, 0);
            o[dt][1] = __builtin_amdgcn_mfma_f32_16x16x32_bf16(va.v, pb1, o[dt][1], 0, 0, 0);
        }
        __builtin_amdgcn_s_setprio(0);
    }
}

__global__ __launch_bounds__(512, 4) void fused_attn(
    const float* __restrict__ query, const float* __restrict__ key,
    const float* __restrict__ value, const int* __restrict__ q_idx,
    const int* __restrict__ k_idx, const int* __restrict__ sampled,
    float* __restrict__ out)
{
    __shared__ __align__(16) short Ksm[16384];   // 32 KB
    __shared__ __align__(16) short Vsm[16384];   // 32 KB
    int wgid = blockIdx.x;
    int wg = (wgid & 7) * 64 + (wgid >> 3);      // bijective XCD swizzle
    int bh = wg >> 4, blk = wg & 15;
    int tid = threadIdx.x, w = tid >> 6, l = tid & 63, lg = l >> 4, ll = l & 15;
    size_t base = (size_t)bh * N_;

    const int* kidxA = k_idx + base + blk * 256;
    const int* kidxB = sampled + bh * SAMP_;

    // staging decomposition
    int rK = tid & 255, hK = tid >> 8;
    int kwofs = (rK >> 4) * 1024 + hK * 512 + (rK & 15) * 8;
    int l6 = tid & 63, i6 = tid >> 6;
    int vrow = (i6 >> 2) * 32 + (l6 >> 5) * 4 + ((l6 >> 1) & 3) + (i6 & 3) * 8;
    int vd   = (((l6 >> 3) & 3) * 2 + (l6 & 1)) * 8;

    // phase A indices
    int krA = kidxA[rK];
    int vA0 = kidxA[vrow],       vA1 = kidxA[64 + vrow];
    int vA2 = kidxA[128 + vrow], vA3 = kidxA[192 + vrow];

    // Q fragments (wave owns 32 queries)
    const int* qidx = q_idx + base + blk * 256 + w * 32;
    int qr[2]; bf16x8 qf[2][2];
#pragma unroll
    for (int mt = 0; mt < 2; ++mt) {
        qr[mt] = qidx[mt * 16 + ll];
        const float* qp = query + (base + (size_t)qr[mt]) * D_;
#pragma unroll
        for (int ks = 0; ks < 2; ++ks)
            qf[mt][ks] = cvt8(qp + ks * 32 + lg * 8);
    }

    f32x4 o[4][2]; float lsum[2];
#pragma unroll
    for (int mt = 0; mt < 2; ++mt) {
        lsum[mt] = 0.f;
#pragma unroll
        for (int dt = 0; dt < 4; ++dt) { f32x4 z = {0.f,0.f,0.f,0.f}; o[dt][mt] = z; }
    }
    unsigned vtr = (unsigned)(unsigned long long)(void*)&Vsm[0] + lg * 512 + ll * 8;

    // ---- phase A: stage, sync, compute (B indices prefetched under compute)
    stage_kv(key, value, base, krA, vA0, vA1, vA2, vA3, hK, kwofs, vd, tid, Ksm, Vsm);
    __syncthreads();

    int krB = kidxB[rK];
    int vB0 = kidxB[vrow],       vB1 = kidxB[64 + vrow];
    int vB2 = kidxB[128 + vrow], vB3 = kidxB[192 + vrow];

    compute_256(Ksm, vtr, 0.f, qf, lg, ll, o, lsum);
    __syncthreads();

    // ---- phase B
    stage_kv(key, value, base, krB, vB0, vB1, vB2, vB3, hK, kwofs, vd, tid, Ksm, Vsm);
    __syncthreads();
    compute_256(Ksm, vtr, LOG16_, qf, lg, ll, o, lsum);

    // ---- row-sum over lg groups; epilogue out = o / l
#pragma unroll
    for (int mt = 0; mt < 2; ++mt) {
        float v = lsum[mt];
        v += __shfl_xor(v, 16);
        v += __shfl_xor(v, 32);
        lsum[mt] = v;
    }
#pragma unroll
    for (int mt = 0; mt < 2; ++mt) {
        float dn = 1.f / lsum[mt];
        float* orow = out + (base + (size_t)qr[mt]) * D_ + lg * 4;
#pragma unroll
        for (int dt = 0; dt < 4; ++dt) {
            f32x4 v = o[dt][mt] * dn;
            *(f32x4*)&orow[dt * 16] = v;
        }
    }
}

// ---------------------------------------------------------------------------
extern "C" void kernel_launch(void* const* d_in, const int* in_sizes, int n_in,
                              void* d_out, int out_size, void* d_ws, size_t ws_size,
                              hipStream_t stream)
{
    const float* query = (const float*)d_in[0];
    const float* key   = (const float*)d_in[1];
    const float* value = (const float*)d_in[2];
    const float* pd    = (const float*)d_in[3];
    const int*   samp  = (const int*)d_in[4];
    float* out = (float*)d_out;

    char* ws = (char*)d_ws;
    unsigned char* qbuck = (unsigned char*)ws;                 // 128 KB
    unsigned char* kbuck = qbuck + (size_t)BH_ * N_;           // 128 KB
    int* q_idx = (int*)(ws + 262144);                          // 512 KB
    int* k_idx = (int*)(ws + 262144 + 524288);                 // 512 KB

    size_t hash_lds = 128 * HPAD * 4 + 512 * 8;
    hipLaunchKernelGGL(hash_kernel, dim3(BH_ * N_ / 128, 2), dim3(128),
                       hash_lds, stream, query, key, pd, qbuck, kbuck);
    hipLaunchKernelGGL(sort_kernel, dim3(BH_, 2), dim3(256), 0, stream,
                       qbuck, kbuck, q_idx, k_idx);
    hipLaunchKernelGGL(fused_attn, dim3(512), dim3(512), 0, stream,
                       query, key, value, q_idx, k_idx, samp, out);
}